// Round 1
// baseline (487.341 us; speedup 1.0000x reference)
//
#include <hip/hip_runtime.h>
#include <hip/hip_bf16.h>

typedef unsigned int uint32;
typedef unsigned short ushort16;
using short8 = __attribute__((ext_vector_type(8))) short;
using f32x4  = __attribute__((ext_vector_type(4))) float;

#define B_ 32
#define C_ 256
#define M_ 4096

__device__ inline ushort f2bf(float f) {
  uint32 u = __builtin_bit_cast(uint32, f);
  u += 0x7FFFu + ((u >> 16) & 1u);   // round-to-nearest-even
  return (ushort)(u >> 16);
}

// ---------------------------------------------------------------------------
// covpool: cov[b] = (X - mean) (X - mean)^T / M  == G/M - mu mu^T
// grid = 32 batches * 4 tiles (128x128), block = 256 threads (4 waves)
// ---------------------------------------------------------------------------
__global__ __launch_bounds__(256)
void covpool_kernel(const float* __restrict__ x, float* __restrict__ cov) {
  const int bid = blockIdx.x;
  const int b  = bid >> 2;
  const int rb = ((bid >> 1) & 1) * 128;
  const int cb = (bid & 1) * 128;
  const float* Xr = x + (size_t)b * C_ * M_ + (size_t)rb * M_;
  const float* Xc = x + (size_t)b * C_ * M_ + (size_t)cb * M_;

  __shared__ ushort As[128 * 64];
  __shared__ ushort Bs[128 * 64];
  __shared__ float rsA[128], rsB[128];

  const int t    = threadIdx.x;
  const int lane = t & 63;
  const int wid  = t >> 6;
  const int wr   = wid >> 1, wc = wid & 1;
  const int r0   = t >> 3;     // rows r0 + 32*i
  const int c8   = t & 7;      // 8-float column chunk

  float sA[4] = {0.f, 0.f, 0.f, 0.f};
  float sB[4] = {0.f, 0.f, 0.f, 0.f};
  f32x4 acc[4][4];
#pragma unroll
  for (int m = 0; m < 4; ++m)
#pragma unroll
    for (int n = 0; n < 4; ++n) acc[m][n] = f32x4{0.f, 0.f, 0.f, 0.f};

  for (int k0 = 0; k0 < M_; k0 += 64) {
    __syncthreads();
#pragma unroll
    for (int i = 0; i < 4; ++i) {
      const int row = r0 + 32 * i;
      const int swz = (c8 * 16) ^ ((row & 7) << 4);
      {
        const float4 a0 = *(const float4*)(Xr + (size_t)row * M_ + k0 + c8 * 8);
        const float4 a1 = *(const float4*)(Xr + (size_t)row * M_ + k0 + c8 * 8 + 4);
        sA[i] += a0.x + a0.y + a0.z + a0.w + a1.x + a1.y + a1.z + a1.w;
        short8 h;
        h[0] = (short)f2bf(a0.x); h[1] = (short)f2bf(a0.y);
        h[2] = (short)f2bf(a0.z); h[3] = (short)f2bf(a0.w);
        h[4] = (short)f2bf(a1.x); h[5] = (short)f2bf(a1.y);
        h[6] = (short)f2bf(a1.z); h[7] = (short)f2bf(a1.w);
        *(short8*)((char*)As + row * 128 + swz) = h;
      }
      {
        const float4 b0 = *(const float4*)(Xc + (size_t)row * M_ + k0 + c8 * 8);
        const float4 b1 = *(const float4*)(Xc + (size_t)row * M_ + k0 + c8 * 8 + 4);
        sB[i] += b0.x + b0.y + b0.z + b0.w + b1.x + b1.y + b1.z + b1.w;
        short8 g;
        g[0] = (short)f2bf(b0.x); g[1] = (short)f2bf(b0.y);
        g[2] = (short)f2bf(b0.z); g[3] = (short)f2bf(b0.w);
        g[4] = (short)f2bf(b1.x); g[5] = (short)f2bf(b1.y);
        g[6] = (short)f2bf(b1.z); g[7] = (short)f2bf(b1.w);
        *(short8*)((char*)Bs + row * 128 + swz) = g;
      }
    }
    __syncthreads();
#pragma unroll
    for (int kk = 0; kk < 2; ++kk) {
      short8 af[4], bfr[4];
      const int slot = kk * 4 + (lane >> 4);
#pragma unroll
      for (int m = 0; m < 4; ++m) {
        const int ar = wr * 64 + m * 16 + (lane & 15);
        af[m] = *(const short8*)((const char*)As + ar * 128 + ((slot * 16) ^ ((ar & 7) << 4)));
      }
#pragma unroll
      for (int n = 0; n < 4; ++n) {
        const int br = wc * 64 + n * 16 + (lane & 15);
        bfr[n] = *(const short8*)((const char*)Bs + br * 128 + ((slot * 16) ^ ((br & 7) << 4)));
      }
#pragma unroll
      for (int m = 0; m < 4; ++m)
#pragma unroll
        for (int n = 0; n < 4; ++n)
          acc[m][n] = __builtin_amdgcn_mfma_f32_16x16x32_bf16(af[m], bfr[n], acc[m][n], 0, 0, 0);
    }
  }

  // reduce row sums across the 8 threads sharing each row (lanes differ in bits 0..2)
#pragma unroll
  for (int i = 0; i < 4; ++i) {
    float v = sA[i];
    v += __shfl_xor(v, 1); v += __shfl_xor(v, 2); v += __shfl_xor(v, 4);
    float w = sB[i];
    w += __shfl_xor(w, 1); w += __shfl_xor(w, 2); w += __shfl_xor(w, 4);
    if ((lane & 7) == 0) { rsA[r0 + 32 * i] = v; rsB[r0 + 32 * i] = w; }
  }
  __syncthreads();

  const float invM = 1.0f / (float)M_;
  float* Co = cov + ((size_t)b << 16);
#pragma unroll
  for (int m = 0; m < 4; ++m)
#pragma unroll
    for (int n = 0; n < 4; ++n)
#pragma unroll
      for (int r = 0; r < 4; ++r) {
        const int lr = wr * 64 + m * 16 + ((lane >> 4) * 4) + r;
        const int lc = wc * 64 + n * 16 + (lane & 15);
        const float mi = rsA[lr] * invM;
        const float mj = rsB[lc] * invM;
        Co[(size_t)(rb + lr) * C_ + (cb + lc)] = acc[m][n][r] * invM - mi * mj;
      }
}

// ---------------------------------------------------------------------------
// trace: normA = trace(cov[b]); store 1/normA and sqrt(normA)
// ---------------------------------------------------------------------------
__global__ __launch_bounds__(256)
void trace_kernel(const float* __restrict__ cov, float* __restrict__ invn,
                  float* __restrict__ sqrtn) {
  const int b = blockIdx.x;
  const int t = threadIdx.x;
  float v = cov[((size_t)b << 16) + (size_t)t * 257];
#pragma unroll
  for (int o = 32; o > 0; o >>= 1) v += __shfl_xor(v, o);
  __shared__ float wsum[4];
  if ((t & 63) == 0) wsum[t >> 6] = v;
  __syncthreads();
  if (t == 0) {
    const float n = wsum[0] + wsum[1] + wsum[2] + wsum[3];
    invn[b]  = 1.0f / n;
    sqrtn[b] = sqrtf(n);
  }
}

// ---------------------------------------------------------------------------
// prep: Y0 = cov/normA ; Z1 = 1.5 I - 0.5 Y0   (Z after the i=0 iteration)
// ---------------------------------------------------------------------------
__global__ __launch_bounds__(256)
void prep_kernel(const float* __restrict__ cov, const float* __restrict__ invn,
                 float* __restrict__ Y, float* __restrict__ Z) {
  const int idx = blockIdx.x * 256 + threadIdx.x;   // float4 index, 524288 total
  const int b  = idx >> 14;
  const int w4 = idx & 16383;
  const int i  = w4 >> 6;
  const int j  = (w4 & 63) * 4;
  const float in = invn[b];
  const float4 c = ((const float4*)cov)[idx];
  float4 y = { c.x * in, c.y * in, c.z * in, c.w * in };
  float4 z = { (j + 0 == i ? 1.5f : 0.f) - 0.5f * y.x,
               (j + 1 == i ? 1.5f : 0.f) - 0.5f * y.y,
               (j + 2 == i ? 1.5f : 0.f) - 0.5f * y.z,
               (j + 3 == i ? 1.5f : 0.f) - 0.5f * y.w };
  ((float4*)Y)[idx] = y;
  ((float4*)Z)[idx] = z;
}

// ---------------------------------------------------------------------------
// gemm_ns: batched 256x256x256 with bf16 MFMA; B operand read row-major
// (all matrices symmetric). Modes:
//   MODE_T : O0 = 1.5 I - 0.5 * (A0 @ Bm)
//   MODE_W : O0 = A0 @ Bm ; O1 = A1 @ Bm (blocks 128..255)
//   MODE_I0: O0 = 1.5 * A0 - 0.5 * (A0 @ Bm)   (elementwise A0 term)
// ---------------------------------------------------------------------------
#define MODE_T 0
#define MODE_W 1
#define MODE_I0 2

template <int MODE>
__global__ __launch_bounds__(256)
void gemm_ns(const float* __restrict__ A0, const float* __restrict__ A1,
             const float* __restrict__ Bm,
             float* __restrict__ O0, float* __restrict__ O1) {
  int bid = blockIdx.x;
  const float* Aall = A0;
  float* Oall = O0;
  if (MODE == MODE_W && bid >= 128) { bid -= 128; Aall = A1; Oall = O1; }
  const int b  = bid >> 2;
  const int rb = ((bid >> 1) & 1) * 128;
  const int cb = (bid & 1) * 128;
  const float* Ap = Aall + ((size_t)b << 16) + rb * C_;
  const float* Bp = Bm   + ((size_t)b << 16) + cb * C_;
  float* Op = Oall + ((size_t)b << 16);

  __shared__ ushort As[128 * 64];
  __shared__ ushort Bs[128 * 64];

  const int t    = threadIdx.x;
  const int lane = t & 63;
  const int wid  = t >> 6;
  const int wr   = wid >> 1, wc = wid & 1;
  const int r0   = t >> 3;
  const int c8   = t & 7;

  f32x4 acc[4][4];
#pragma unroll
  for (int m = 0; m < 4; ++m)
#pragma unroll
    for (int n = 0; n < 4; ++n) acc[m][n] = f32x4{0.f, 0.f, 0.f, 0.f};

#pragma unroll 1
  for (int k0 = 0; k0 < C_; k0 += 64) {
    __syncthreads();
#pragma unroll
    for (int i = 0; i < 4; ++i) {
      const int row = r0 + 32 * i;
      const int swz = (c8 * 16) ^ ((row & 7) << 4);
      {
        const float4 a0 = *(const float4*)(Ap + row * C_ + k0 + c8 * 8);
        const float4 a1 = *(const float4*)(Ap + row * C_ + k0 + c8 * 8 + 4);
        short8 h;
        h[0] = (short)f2bf(a0.x); h[1] = (short)f2bf(a0.y);
        h[2] = (short)f2bf(a0.z); h[3] = (short)f2bf(a0.w);
        h[4] = (short)f2bf(a1.x); h[5] = (short)f2bf(a1.y);
        h[6] = (short)f2bf(a1.z); h[7] = (short)f2bf(a1.w);
        *(short8*)((char*)As + row * 128 + swz) = h;
      }
      {
        const float4 b0 = *(const float4*)(Bp + row * C_ + k0 + c8 * 8);
        const float4 b1 = *(const float4*)(Bp + row * C_ + k0 + c8 * 8 + 4);
        short8 g;
        g[0] = (short)f2bf(b0.x); g[1] = (short)f2bf(b0.y);
        g[2] = (short)f2bf(b0.z); g[3] = (short)f2bf(b0.w);
        g[4] = (short)f2bf(b1.x); g[5] = (short)f2bf(b1.y);
        g[6] = (short)f2bf(b1.z); g[7] = (short)f2bf(b1.w);
        *(short8*)((char*)Bs + row * 128 + swz) = g;
      }
    }
    __syncthreads();
#pragma unroll
    for (int kk = 0; kk < 2; ++kk) {
      short8 af[4], bfr[4];
      const int slot = kk * 4 + (lane >> 4);
#pragma unroll
      for (int m = 0; m < 4; ++m) {
        const int ar = wr * 64 + m * 16 + (lane & 15);
        af[m] = *(const short8*)((const char*)As + ar * 128 + ((slot * 16) ^ ((ar & 7) << 4)));
      }
#pragma unroll
      for (int n = 0; n < 4; ++n) {
        const int br = wc * 64 + n * 16 + (lane & 15);
        bfr[n] = *(const short8*)((const char*)Bs + br * 128 + ((slot * 16) ^ ((br & 7) << 4)));
      }
#pragma unroll
      for (int m = 0; m < 4; ++m)
#pragma unroll
        for (int n = 0; n < 4; ++n)
          acc[m][n] = __builtin_amdgcn_mfma_f32_16x16x32_bf16(af[m], bfr[n], acc[m][n], 0, 0, 0);
    }
  }

#pragma unroll
  for (int m = 0; m < 4; ++m)
#pragma unroll
    for (int n = 0; n < 4; ++n)
#pragma unroll
      for (int r = 0; r < 4; ++r) {
        const int lr = wr * 64 + m * 16 + ((lane >> 4) * 4) + r;
        const int lc = wc * 64 + n * 16 + (lane & 15);
        const float v = acc[m][n][r];
        float o;
        if (MODE == MODE_T)       o = (((rb + lr) == (cb + lc)) ? 1.5f : 0.0f) - 0.5f * v;
        else if (MODE == MODE_W)  o = v;
        else /* MODE_I0 */        o = 1.5f * Ap[lr * C_ + (cb + lc)] - 0.5f * v;
        Op[(size_t)(rb + lr) * C_ + (cb + lc)] = o;
      }
}

// ---------------------------------------------------------------------------
// final: u = colmean(Y); v = sqrtn * (u^T T); MLP -> a[b][c]
// ---------------------------------------------------------------------------
__global__ __launch_bounds__(256)
void final_kernel(const float* __restrict__ Y, const float* __restrict__ T,
                  const float* __restrict__ sqrtn,
                  const float* __restrict__ w1, const float* __restrict__ b1,
                  const float* __restrict__ w2, const float* __restrict__ b2,
                  float* __restrict__ a) {
  const int b = blockIdx.x;
  const int c = threadIdx.x;
  __shared__ float u[C_], vv[C_], h[32];
  const float* Yb = Y + ((size_t)b << 16);
  const float* Tb = T + ((size_t)b << 16);

  float s = 0.f;
  for (int i = 0; i < C_; ++i) s += Yb[(size_t)i * C_ + c];
  u[c] = s * (1.0f / (float)C_);
  __syncthreads();

  float acc = 0.f;
  for (int k = 0; k < C_; ++k) acc += u[k] * Tb[(size_t)k * C_ + c];
  vv[c] = acc * sqrtn[b];
  __syncthreads();

  if (c < 32) {
    float hh = b1[c];
    for (int k = 0; k < C_; ++k) hh += w1[c * C_ + k] * vv[k];
    h[c] = fmaxf(hh, 0.0f);
  }
  __syncthreads();

  float aa = b2[c];
#pragma unroll
  for (int o = 0; o < 32; ++o) aa += w2[c * 32 + o] * h[o];
  a[b * C_ + c] = 1.0f / (1.0f + expf(-aa));
}

// ---------------------------------------------------------------------------
// scale: out = a[b][c] * x
// ---------------------------------------------------------------------------
__global__ __launch_bounds__(256)
void scale_kernel(const float* __restrict__ x, const float* __restrict__ a,
                  float* __restrict__ out) {
  const int stride = gridDim.x * blockDim.x;
  const int n4 = B_ * C_ * M_ / 4;   // 8388608
  for (int i = blockIdx.x * blockDim.x + threadIdx.x; i < n4; i += stride) {
    const float4 v = ((const float4*)x)[i];
    const float s = a[i >> 10];      // 1024 float4 per (b,c) row
    float4 o = { v.x * s, v.y * s, v.z * s, v.w * s };
    ((float4*)out)[i] = o;
  }
}

// ---------------------------------------------------------------------------
extern "C" void kernel_launch(void* const* d_in, const int* in_sizes, int n_in,
                              void* d_out, int out_size, void* d_ws, size_t ws_size,
                              hipStream_t stream) {
  const float* x  = (const float*)d_in[0];
  const float* w1 = (const float*)d_in[1];
  const float* b1 = (const float*)d_in[2];
  const float* w2 = (const float*)d_in[3];
  const float* b2 = (const float*)d_in[4];
  float* out = (float*)d_out;

  float* ws = (float*)d_ws;
  const size_t MAT = (size_t)B_ * C_ * C_;   // 2,097,152 floats per matrix set
  float* covT = ws;             // cov, later reused as T
  float* YA   = ws + 1 * MAT;
  float* YB   = ws + 2 * MAT;
  float* ZA   = ws + 3 * MAT;
  float* ZB   = ws + 4 * MAT;
  float* invn  = ws + 5 * MAT;
  float* sqrtn = invn + 32;
  float* a     = sqrtn + 32;    // 32*256

  covpool_kernel<<<128, 256, 0, stream>>>(x, covT);
  trace_kernel<<<32, 256, 0, stream>>>(covT, invn, sqrtn);
  prep_kernel<<<2048, 256, 0, stream>>>(covT, invn, YA, ZA);

  // i=0 (Z=I): Y1 = 1.5 Y0 - 0.5 Y0@Y0 ; Z1 = 1.5I - 0.5 Y0 (done in prep)
  gemm_ns<MODE_I0><<<128, 256, 0, stream>>>(YA, nullptr, YA, YB, nullptr);
  // i=1: Y=YB, Z=ZA
  gemm_ns<MODE_T><<<128, 256, 0, stream>>>(ZA, nullptr, YB, covT, nullptr);
  gemm_ns<MODE_W><<<256, 256, 0, stream>>>(YB, ZA, covT, YA, ZB);
  // i=2: Y=YA, Z=ZB
  gemm_ns<MODE_T><<<128, 256, 0, stream>>>(ZB, nullptr, YA, covT, nullptr);
  gemm_ns<MODE_W><<<256, 256, 0, stream>>>(YA, ZB, covT, YB, ZA);
  // i=3: Y=YB, Z=ZA
  gemm_ns<MODE_T><<<128, 256, 0, stream>>>(ZA, nullptr, YB, covT, nullptr);
  gemm_ns<MODE_W><<<256, 256, 0, stream>>>(YB, ZA, covT, YA, ZB);
  // i=4: Y=YA, Z=ZB; only T needed, then v = colmean(Y)^T @ T
  gemm_ns<MODE_T><<<128, 256, 0, stream>>>(ZB, nullptr, YA, covT, nullptr);

  final_kernel<<<32, 256, 0, stream>>>(YA, covT, sqrtn, w1, b1, w2, b2, a);
  scale_kernel<<<4096, 256, 0, stream>>>(x, a, out);
}

// Round 2
// 420.546 us; speedup vs baseline: 1.1588x; 1.1588x over previous
//
#include <hip/hip_runtime.h>
#include <hip/hip_bf16.h>

typedef unsigned int uint32;
using short8 = __attribute__((ext_vector_type(8))) short;
using f32x4  = __attribute__((ext_vector_type(4))) float;

#define B_ 32
#define C_ 256
#define M_ 4096

__device__ inline ushort f2bf(float f) {
  uint32 u = __builtin_bit_cast(uint32, f);
  u += 0x7FFFu + ((u >> 16) & 1u);   // round-to-nearest-even
  return (ushort)(u >> 16);
}

// ---------------------------------------------------------------------------
// covpool partial: G_s[b] += Xr[:,ks] @ Xc[:,ks]^T  (raw, no mean, no /M)
// grid = 32 b * 4 tiles * 4 ksplits = 512 blocks; 256 thr (4 waves)
// also writes per-row sums rs[b][s][row] (over its k-range)
// ---------------------------------------------------------------------------
__global__ __launch_bounds__(256)
void covpool_kernel(const float* __restrict__ x,
                    float* __restrict__ p0, float* __restrict__ p1,
                    float* __restrict__ p2, float* __restrict__ p3,
                    float* __restrict__ rs) {
  const int bid0 = blockIdx.x;
  const int bid  = (bid0 & 7) * 64 + (bid0 >> 3);   // chunked XCD swizzle (512%8==0)
  const int b    = bid >> 4;
  const int tile = (bid >> 2) & 3;
  const int s    = bid & 3;
  const int rb   = (tile >> 1) * 128;
  const int cb   = (tile & 1) * 128;
  const int kb   = s * 1024;
  float* P = (s == 0) ? p0 : (s == 1) ? p1 : (s == 2) ? p2 : p3;

  const float* Xr = x + (size_t)b * C_ * M_ + (size_t)rb * M_;
  const float* Xc = x + (size_t)b * C_ * M_ + (size_t)cb * M_;

  __shared__ ushort As[128 * 64];
  __shared__ ushort Bs[128 * 64];

  const int t    = threadIdx.x;
  const int lane = t & 63;
  const int wid  = t >> 6;
  const int wr   = wid >> 1, wc = wid & 1;
  const int r0   = t >> 3;     // rows r0 + 32*i
  const int c8   = t & 7;      // 8-float column chunk

  float sA[4] = {0.f, 0.f, 0.f, 0.f};
  f32x4 acc[4][4];
#pragma unroll
  for (int m = 0; m < 4; ++m)
#pragma unroll
    for (int n = 0; n < 4; ++n) acc[m][n] = f32x4{0.f, 0.f, 0.f, 0.f};

  for (int k0 = kb; k0 < kb + 1024; k0 += 64) {
    __syncthreads();
#pragma unroll
    for (int i = 0; i < 4; ++i) {
      const int row = r0 + 32 * i;
      const int swz = (c8 * 16) ^ ((row & 7) << 4);
      {
        const float4 a0 = *(const float4*)(Xr + (size_t)row * M_ + k0 + c8 * 8);
        const float4 a1 = *(const float4*)(Xr + (size_t)row * M_ + k0 + c8 * 8 + 4);
        sA[i] += a0.x + a0.y + a0.z + a0.w + a1.x + a1.y + a1.z + a1.w;
        short8 h;
        h[0] = (short)f2bf(a0.x); h[1] = (short)f2bf(a0.y);
        h[2] = (short)f2bf(a0.z); h[3] = (short)f2bf(a0.w);
        h[4] = (short)f2bf(a1.x); h[5] = (short)f2bf(a1.y);
        h[6] = (short)f2bf(a1.z); h[7] = (short)f2bf(a1.w);
        *(short8*)((char*)As + row * 128 + swz) = h;
      }
      {
        const float4 b0 = *(const float4*)(Xc + (size_t)row * M_ + k0 + c8 * 8);
        const float4 b1 = *(const float4*)(Xc + (size_t)row * M_ + k0 + c8 * 8 + 4);
        short8 g;
        g[0] = (short)f2bf(b0.x); g[1] = (short)f2bf(b0.y);
        g[2] = (short)f2bf(b0.z); g[3] = (short)f2bf(b0.w);
        g[4] = (short)f2bf(b1.x); g[5] = (short)f2bf(b1.y);
        g[6] = (short)f2bf(b1.z); g[7] = (short)f2bf(b1.w);
        *(short8*)((char*)Bs + row * 128 + swz) = g;
      }
    }
    __syncthreads();
#pragma unroll
    for (int kk = 0; kk < 2; ++kk) {
      short8 af[4], bfr[4];
      const int slot = kk * 4 + (lane >> 4);
#pragma unroll
      for (int m = 0; m < 4; ++m) {
        const int ar = wr * 64 + m * 16 + (lane & 15);
        af[m] = *(const short8*)((const char*)As + ar * 128 + ((slot * 16) ^ ((ar & 7) << 4)));
      }
#pragma unroll
      for (int n = 0; n < 4; ++n) {
        const int br = wc * 64 + n * 16 + (lane & 15);
        bfr[n] = *(const short8*)((const char*)Bs + br * 128 + ((slot * 16) ^ ((br & 7) << 4)));
      }
#pragma unroll
      for (int m = 0; m < 4; ++m)
#pragma unroll
        for (int n = 0; n < 4; ++n)
          acc[m][n] = __builtin_amdgcn_mfma_f32_16x16x32_bf16(af[m], bfr[n], acc[m][n], 0, 0, 0);
    }
  }

  // row sums for this k-slice (rows rb..rb+127); both cb-blocks write identical
  // values -> benign duplicate write.
#pragma unroll
  for (int i = 0; i < 4; ++i) {
    float v = sA[i];
    v += __shfl_xor(v, 1); v += __shfl_xor(v, 2); v += __shfl_xor(v, 4);
    if ((lane & 7) == 0) rs[b * 1024 + s * 256 + rb + r0 + 32 * i] = v;
  }

  float* Po = P + ((size_t)b << 16);
#pragma unroll
  for (int m = 0; m < 4; ++m)
#pragma unroll
    for (int n = 0; n < 4; ++n)
#pragma unroll
      for (int r = 0; r < 4; ++r) {
        const int lr = wr * 64 + m * 16 + ((lane >> 4) * 4) + r;
        const int lc = wc * 64 + n * 16 + (lane & 15);
        Po[(size_t)(rb + lr) * C_ + (cb + lc)] = acc[m][n][r];
      }
}

// ---------------------------------------------------------------------------
// reduce: cov = (p0+p1+p2+p3)/M - mu mu^T,  mu_i = (sum_s rs[b][s][i])/M
// grid 2048 x 256, one float4 per thread
// ---------------------------------------------------------------------------
__global__ __launch_bounds__(256)
void reduce_kernel(const float* __restrict__ p0, const float* __restrict__ p1,
                   const float* __restrict__ p2, const float* __restrict__ p3,
                   const float* __restrict__ rs, float* __restrict__ cov) {
  const int idx = blockIdx.x * 256 + threadIdx.x;   // float4 index, 524288 total
  const int b   = idx >> 14;
  const int rem = idx & 16383;
  const int i   = rem >> 6;
  const int j4  = (rem & 63) * 4;
  const float invM = 1.0f / (float)M_;

  const float4 g0 = ((const float4*)p0)[idx];
  const float4 g1 = ((const float4*)p1)[idx];
  const float4 g2 = ((const float4*)p2)[idx];
  const float4 g3 = ((const float4*)p3)[idx];

  const float* rb_ = rs + b * 1024;
  const float mi = (rb_[i] + rb_[256 + i] + rb_[512 + i] + rb_[768 + i]) * invM;
  const float4 s0 = *(const float4*)(rb_ + j4);
  const float4 s1 = *(const float4*)(rb_ + 256 + j4);
  const float4 s2 = *(const float4*)(rb_ + 512 + j4);
  const float4 s3 = *(const float4*)(rb_ + 768 + j4);

  float4 o;
  o.x = (g0.x + g1.x + g2.x + g3.x) * invM - mi * ((s0.x + s1.x + s2.x + s3.x) * invM);
  o.y = (g0.y + g1.y + g2.y + g3.y) * invM - mi * ((s0.y + s1.y + s2.y + s3.y) * invM);
  o.z = (g0.z + g1.z + g2.z + g3.z) * invM - mi * ((s0.z + s1.z + s2.z + s3.z) * invM);
  o.w = (g0.w + g1.w + g2.w + g3.w) * invM - mi * ((s0.w + s1.w + s2.w + s3.w) * invM);
  ((float4*)cov)[idx] = o;
}

// ---------------------------------------------------------------------------
// trace: normA = trace(cov[b]); store 1/normA and sqrt(normA)
// ---------------------------------------------------------------------------
__global__ __launch_bounds__(256)
void trace_kernel(const float* __restrict__ cov, float* __restrict__ invn,
                  float* __restrict__ sqrtn) {
  const int b = blockIdx.x;
  const int t = threadIdx.x;
  float v = cov[((size_t)b << 16) + (size_t)t * 257];
#pragma unroll
  for (int o = 32; o > 0; o >>= 1) v += __shfl_xor(v, o);
  __shared__ float wsum[4];
  if ((t & 63) == 0) wsum[t >> 6] = v;
  __syncthreads();
  if (t == 0) {
    const float n = wsum[0] + wsum[1] + wsum[2] + wsum[3];
    invn[b]  = 1.0f / n;
    sqrtn[b] = sqrtf(n);
  }
}

// ---------------------------------------------------------------------------
// prep: Y0 = cov/normA ; Z1 = 1.5 I - 0.5 Y0   (Z after the i=0 iteration)
// ---------------------------------------------------------------------------
__global__ __launch_bounds__(256)
void prep_kernel(const float* __restrict__ cov, const float* __restrict__ invn,
                 float* __restrict__ Y, float* __restrict__ Z) {
  const int idx = blockIdx.x * 256 + threadIdx.x;   // float4 index, 524288 total
  const int b  = idx >> 14;
  const int w4 = idx & 16383;
  const int i  = w4 >> 6;
  const int j  = (w4 & 63) * 4;
  const float in = invn[b];
  const float4 c = ((const float4*)cov)[idx];
  float4 y = { c.x * in, c.y * in, c.z * in, c.w * in };
  float4 z = { (j + 0 == i ? 1.5f : 0.f) - 0.5f * y.x,
               (j + 1 == i ? 1.5f : 0.f) - 0.5f * y.y,
               (j + 2 == i ? 1.5f : 0.f) - 0.5f * y.z,
               (j + 3 == i ? 1.5f : 0.f) - 0.5f * y.w };
  ((float4*)Y)[idx] = y;
  ((float4*)Z)[idx] = z;
}

// ---------------------------------------------------------------------------
// gemm_ns: batched 256x256x256, 64x64 tiles (16/batch) for occupancy.
// B operand read row-major (all matrices symmetric). Modes:
//   MODE_T : O0 = 1.5 I - 0.5 * (A0 @ Bm)          grid 512
//   MODE_W : O0 = A0 @ Bm ; O1 = A1 @ Bm           grid 1024
//   MODE_I0: O0 = 1.5 * A0 - 0.5 * (A0 @ Bm)       grid 512
// ---------------------------------------------------------------------------
#define MODE_T 0
#define MODE_W 1
#define MODE_I0 2

template <int MODE>
__global__ __launch_bounds__(256)
void gemm_ns(const float* __restrict__ A0, const float* __restrict__ A1,
             const float* __restrict__ Bm,
             float* __restrict__ O0, float* __restrict__ O1) {
  int bid = blockIdx.x;
  const float* Aall = A0;
  float* Oall = O0;
  if (MODE == MODE_W && bid >= 512) { bid -= 512; Aall = A1; Oall = O1; }
  const int b    = bid >> 4;
  const int tile = bid & 15;
  const int rb   = (tile >> 2) * 64;
  const int cb   = (tile & 3) * 64;
  const float* Ap = Aall + ((size_t)b << 16) + rb * C_;
  const float* Bp = Bm   + ((size_t)b << 16) + cb * C_;
  float* Op = Oall + ((size_t)b << 16);

  __shared__ ushort As[64 * 64];
  __shared__ ushort Bs[64 * 64];

  const int t    = threadIdx.x;
  const int lane = t & 63;
  const int wid  = t >> 6;
  const int wr   = wid >> 1, wc = wid & 1;   // wave -> 32x32 subtile
  const int r0   = t >> 3;                   // rows r0, r0+32
  const int c8   = t & 7;

  f32x4 acc[2][2];
#pragma unroll
  for (int m = 0; m < 2; ++m)
#pragma unroll
    for (int n = 0; n < 2; ++n) acc[m][n] = f32x4{0.f, 0.f, 0.f, 0.f};

#pragma unroll 1
  for (int k0 = 0; k0 < C_; k0 += 64) {
    __syncthreads();
#pragma unroll
    for (int i = 0; i < 2; ++i) {
      const int row = r0 + 32 * i;
      const int swz = (c8 * 16) ^ ((row & 7) << 4);
      {
        const float4 a0 = *(const float4*)(Ap + row * C_ + k0 + c8 * 8);
        const float4 a1 = *(const float4*)(Ap + row * C_ + k0 + c8 * 8 + 4);
        short8 h;
        h[0] = (short)f2bf(a0.x); h[1] = (short)f2bf(a0.y);
        h[2] = (short)f2bf(a0.z); h[3] = (short)f2bf(a0.w);
        h[4] = (short)f2bf(a1.x); h[5] = (short)f2bf(a1.y);
        h[6] = (short)f2bf(a1.z); h[7] = (short)f2bf(a1.w);
        *(short8*)((char*)As + row * 128 + swz) = h;
      }
      {
        const float4 b0 = *(const float4*)(Bp + row * C_ + k0 + c8 * 8);
        const float4 b1 = *(const float4*)(Bp + row * C_ + k0 + c8 * 8 + 4);
        short8 g;
        g[0] = (short)f2bf(b0.x); g[1] = (short)f2bf(b0.y);
        g[2] = (short)f2bf(b0.z); g[3] = (short)f2bf(b0.w);
        g[4] = (short)f2bf(b1.x); g[5] = (short)f2bf(b1.y);
        g[6] = (short)f2bf(b1.z); g[7] = (short)f2bf(b1.w);
        *(short8*)((char*)Bs + row * 128 + swz) = g;
      }
    }
    __syncthreads();
#pragma unroll
    for (int kk = 0; kk < 2; ++kk) {
      short8 af[2], bfr[2];
      const int slot = kk * 4 + (lane >> 4);
#pragma unroll
      for (int m = 0; m < 2; ++m) {
        const int ar = wr * 32 + m * 16 + (lane & 15);
        af[m] = *(const short8*)((const char*)As + ar * 128 + ((slot * 16) ^ ((ar & 7) << 4)));
      }
#pragma unroll
      for (int n = 0; n < 2; ++n) {
        const int br = wc * 32 + n * 16 + (lane & 15);
        bfr[n] = *(const short8*)((const char*)Bs + br * 128 + ((slot * 16) ^ ((br & 7) << 4)));
      }
#pragma unroll
      for (int m = 0; m < 2; ++m)
#pragma unroll
        for (int n = 0; n < 2; ++n)
          acc[m][n] = __builtin_amdgcn_mfma_f32_16x16x32_bf16(af[m], bfr[n], acc[m][n], 0, 0, 0);
    }
  }

#pragma unroll
  for (int m = 0; m < 2; ++m)
#pragma unroll
    for (int n = 0; n < 2; ++n)
#pragma unroll
      for (int r = 0; r < 4; ++r) {
        const int lr = wr * 32 + m * 16 + ((lane >> 4) * 4) + r;
        const int lc = wc * 32 + n * 16 + (lane & 15);
        const float v = acc[m][n][r];
        float o;
        if (MODE == MODE_T)       o = (((rb + lr) == (cb + lc)) ? 1.5f : 0.0f) - 0.5f * v;
        else if (MODE == MODE_W)  o = v;
        else /* MODE_I0 */        o = 1.5f * Ap[lr * C_ + (cb + lc)] - 0.5f * v;
        Op[(size_t)(rb + lr) * C_ + (cb + lc)] = o;
      }
}

// ---------------------------------------------------------------------------
// final: u = colmean(Y); v = sqrtn * (u^T T); MLP -> a[b][c]
// ---------------------------------------------------------------------------
__global__ __launch_bounds__(256)
void final_kernel(const float* __restrict__ Y, const float* __restrict__ T,
                  const float* __restrict__ sqrtn,
                  const float* __restrict__ w1, const float* __restrict__ b1,
                  const float* __restrict__ w2, const float* __restrict__ b2,
                  float* __restrict__ a) {
  const int b = blockIdx.x;
  const int c = threadIdx.x;
  __shared__ float u[C_], vv[C_], h[32];
  const float* Yb = Y + ((size_t)b << 16);
  const float* Tb = T + ((size_t)b << 16);

  float s = 0.f;
  for (int i = 0; i < C_; ++i) s += Yb[(size_t)i * C_ + c];
  u[c] = s * (1.0f / (float)C_);
  __syncthreads();

  float acc = 0.f;
  for (int k = 0; k < C_; ++k) acc += u[k] * Tb[(size_t)k * C_ + c];
  vv[c] = acc * sqrtn[b];
  __syncthreads();

  if (c < 32) {
    float hh = b1[c];
    for (int k = 0; k < C_; ++k) hh += w1[c * C_ + k] * vv[k];
    h[c] = fmaxf(hh, 0.0f);
  }
  __syncthreads();

  float aa = b2[c];
#pragma unroll
  for (int o = 0; o < 32; ++o) aa += w2[c * 32 + o] * h[o];
  a[b * C_ + c] = 1.0f / (1.0f + expf(-aa));
}

// ---------------------------------------------------------------------------
// scale: out = a[b][c] * x
// ---------------------------------------------------------------------------
__global__ __launch_bounds__(256)
void scale_kernel(const float* __restrict__ x, const float* __restrict__ a,
                  float* __restrict__ out) {
  const int stride = gridDim.x * blockDim.x;
  const int n4 = B_ * C_ * M_ / 4;   // 8388608
  for (int i = blockIdx.x * blockDim.x + threadIdx.x; i < n4; i += stride) {
    const float4 v = ((const float4*)x)[i];
    const float s = a[i >> 10];      // 1024 float4 per (b,c) row
    float4 o = { v.x * s, v.y * s, v.z * s, v.w * s };
    ((float4*)out)[i] = o;
  }
}

// ---------------------------------------------------------------------------
extern "C" void kernel_launch(void* const* d_in, const int* in_sizes, int n_in,
                              void* d_out, int out_size, void* d_ws, size_t ws_size,
                              hipStream_t stream) {
  const float* x  = (const float*)d_in[0];
  const float* w1 = (const float*)d_in[1];
  const float* b1 = (const float*)d_in[2];
  const float* w2 = (const float*)d_in[3];
  const float* b2 = (const float*)d_in[4];
  float* out = (float*)d_out;

  float* ws = (float*)d_ws;
  const size_t MAT = (size_t)B_ * C_ * C_;   // 2,097,152 floats per matrix set
  float* covT = ws;             // cov, later reused as T
  float* YA   = ws + 1 * MAT;   // also covpool partial 0
  float* YB   = ws + 2 * MAT;   // also covpool partial 1
  float* ZA   = ws + 3 * MAT;   // also covpool partial 2
  float* ZB   = ws + 4 * MAT;   // also covpool partial 3
  float* invn  = ws + 5 * MAT;
  float* sqrtn = invn + 32;
  float* a     = sqrtn + 32;    // 32*256
  float* rs    = a + 32 * 256;  // 32*4*256 row-sum partials

  covpool_kernel<<<512, 256, 0, stream>>>(x, YA, YB, ZA, ZB, rs);
  reduce_kernel<<<2048, 256, 0, stream>>>(YA, YB, ZA, ZB, rs, covT);
  trace_kernel<<<32, 256, 0, stream>>>(covT, invn, sqrtn);
  prep_kernel<<<2048, 256, 0, stream>>>(covT, invn, YA, ZA);

  // i=0 (Z=I): Y1 = 1.5 Y0 - 0.5 Y0@Y0 ; Z1 = 1.5I - 0.5 Y0 (done in prep)
  gemm_ns<MODE_I0><<<512, 256, 0, stream>>>(YA, nullptr, YA, YB, nullptr);
  // i=1: Y=YB, Z=ZA
  gemm_ns<MODE_T><<<512, 256, 0, stream>>>(ZA, nullptr, YB, covT, nullptr);
  gemm_ns<MODE_W><<<1024, 256, 0, stream>>>(YB, ZA, covT, YA, ZB);
  // i=2: Y=YA, Z=ZB
  gemm_ns<MODE_T><<<512, 256, 0, stream>>>(ZB, nullptr, YA, covT, nullptr);
  gemm_ns<MODE_W><<<1024, 256, 0, stream>>>(YA, ZB, covT, YB, ZA);
  // i=3: Y=YB, Z=ZA
  gemm_ns<MODE_T><<<512, 256, 0, stream>>>(ZA, nullptr, YB, covT, nullptr);
  gemm_ns<MODE_W><<<1024, 256, 0, stream>>>(YB, ZA, covT, YA, ZB);
  // i=4: Y=YA, Z=ZB; only T needed, then v = colmean(Y)^T @ T
  gemm_ns<MODE_T><<<512, 256, 0, stream>>>(ZB, nullptr, YA, covT, nullptr);

  final_kernel<<<32, 256, 0, stream>>>(YA, covT, sqrtn, w1, b1, w2, b2, a);
  scale_kernel<<<4096, 256, 0, stream>>>(x, a, out);
}

// Round 3
// 367.945 us; speedup vs baseline: 1.3245x; 1.1430x over previous
//
#include <hip/hip_runtime.h>
#include <hip/hip_bf16.h>

typedef unsigned int uint32;
using short8 = __attribute__((ext_vector_type(8))) short;
using ushort4_t = __attribute__((ext_vector_type(4))) unsigned short;
using f32x4  = __attribute__((ext_vector_type(4))) float;

#define B_ 32
#define C_ 256
#define M_ 4096
#define MATF 2097152      // floats per 32-batch matrix set (32*256*256)

#define AS1 __attribute__((address_space(1)))
#define AS3 __attribute__((address_space(3)))

__device__ inline ushort f2bf(float f) {
  uint32 u = __builtin_bit_cast(uint32, f);
  u += 0x7FFFu + ((u >> 16) & 1u);   // round-to-nearest-even
  return (ushort)(u >> 16);
}
__device__ inline float bf2f(ushort u) {
  uint32 v = ((uint32)u) << 16;
  return __builtin_bit_cast(float, v);
}
__device__ inline void gl_lds16(const ushort* g, ushort* l) {
  __builtin_amdgcn_global_load_lds((const AS1 void*)g, (AS3 void*)l, 16, 0, 0);
}

// ---------------------------------------------------------------------------
// covpool partial: slice s of Gram G[b] = X X^T over k = s*512..+512.
// One block = full 256x256 output, single shared LDS panel (A==B).
// grid 256 (32 b x 8 s), 1024 threads (16 waves, each a 64x64 quadrant).
// ---------------------------------------------------------------------------
__global__ __launch_bounds__(1024)
void covpool_kernel(const float* __restrict__ x, float* __restrict__ parts,
                    float* __restrict__ rs) {
  const int bid = blockIdx.x;
  const int b = bid >> 3, s = bid & 7;
  const int kb = s * 512;
  const float* Xb = x + (size_t)b * C_ * M_;
  float* P = parts + (size_t)s * MATF + ((size_t)b << 16);

  __shared__ ushort As[256 * 64];   // 32 KB

  const int t    = threadIdx.x;
  const int lane = t & 63;
  const int w    = t >> 6;            // 0..15
  const int wr   = w >> 2, wc = w & 3;
  const int row  = t >> 2;            // 0..255
  const int ch   = t & 3;             // 16-float source chunk

  float rsum = 0.f;
  f32x4 acc[4][4];
#pragma unroll
  for (int m = 0; m < 4; ++m)
#pragma unroll
    for (int n = 0; n < 4; ++n) acc[m][n] = f32x4{0.f, 0.f, 0.f, 0.f};

  const int swzbase = (row & 7) << 4;
  char* wbase = (char*)As + row * 128;

  for (int k0 = kb; k0 < kb + 512; k0 += 64) {
    __syncthreads();
    const float* src = Xb + (size_t)row * M_ + k0 + ch * 16;
    const float4 v0 = ((const float4*)src)[0];
    const float4 v1 = ((const float4*)src)[1];
    const float4 v2 = ((const float4*)src)[2];
    const float4 v3 = ((const float4*)src)[3];
    rsum += v0.x + v0.y + v0.z + v0.w + v1.x + v1.y + v1.z + v1.w +
            v2.x + v2.y + v2.z + v2.w + v3.x + v3.y + v3.z + v3.w;
    short8 h0, h1;
    h0[0] = (short)f2bf(v0.x); h0[1] = (short)f2bf(v0.y);
    h0[2] = (short)f2bf(v0.z); h0[3] = (short)f2bf(v0.w);
    h0[4] = (short)f2bf(v1.x); h0[5] = (short)f2bf(v1.y);
    h0[6] = (short)f2bf(v1.z); h0[7] = (short)f2bf(v1.w);
    h1[0] = (short)f2bf(v2.x); h1[1] = (short)f2bf(v2.y);
    h1[2] = (short)f2bf(v2.z); h1[3] = (short)f2bf(v2.w);
    h1[4] = (short)f2bf(v3.x); h1[5] = (short)f2bf(v3.y);
    h1[6] = (short)f2bf(v3.z); h1[7] = (short)f2bf(v3.w);
    const int c0 = ch * 2;
    *(short8*)(wbase + ((c0 * 16) ^ swzbase))       = h0;
    *(short8*)(wbase + (((c0 + 1) * 16) ^ swzbase)) = h1;
    __syncthreads();
#pragma unroll
    for (int kk = 0; kk < 2; ++kk) {
      short8 af[4], bfr[4];
      const int slot = kk * 4 + (lane >> 4);
#pragma unroll
      for (int m = 0; m < 4; ++m) {
        const int ar = wr * 64 + m * 16 + (lane & 15);
        af[m] = *(const short8*)((const char*)As + ar * 128 + ((slot * 16) ^ ((ar & 7) << 4)));
      }
#pragma unroll
      for (int n = 0; n < 4; ++n) {
        const int br = wc * 64 + n * 16 + (lane & 15);
        bfr[n] = *(const short8*)((const char*)As + br * 128 + ((slot * 16) ^ ((br & 7) << 4)));
      }
#pragma unroll
      for (int m = 0; m < 4; ++m)
#pragma unroll
        for (int n = 0; n < 4; ++n)
          acc[m][n] = __builtin_amdgcn_mfma_f32_16x16x32_bf16(af[m], bfr[n], acc[m][n], 0, 0, 0);
    }
  }

  // per-row sums: 4 staging threads per row are consecutive lanes
  rsum += __shfl_xor(rsum, 1);
  rsum += __shfl_xor(rsum, 2);
  if (ch == 0) rs[b * 2048 + s * 256 + row] = rsum;

#pragma unroll
  for (int m = 0; m < 4; ++m)
#pragma unroll
    for (int n = 0; n < 4; ++n)
#pragma unroll
      for (int r = 0; r < 4; ++r) {
        const int lr = wr * 64 + m * 16 + ((lane >> 4) * 4) + r;
        const int lc = wc * 64 + n * 16 + (lane & 15);
        P[(size_t)lr * C_ + lc] = acc[m][n][r];
      }
}

// ---------------------------------------------------------------------------
// trace from partials: n = sum_i (G_ii/M - mu_i^2); invn, sqrtn
// ---------------------------------------------------------------------------
__global__ __launch_bounds__(256)
void trace_kernel(const float* __restrict__ parts, const float* __restrict__ rs,
                  float* __restrict__ invn, float* __restrict__ sqrtn) {
  const int b = blockIdx.x;
  const int i = threadIdx.x;
  const float invM = 1.0f / (float)M_;
  float d = 0.f, m = 0.f;
#pragma unroll
  for (int s = 0; s < 8; ++s) {
    d += parts[(size_t)s * MATF + ((size_t)b << 16) + (size_t)i * 257];
    m += rs[b * 2048 + s * 256 + i];
  }
  const float mu = m * invM;
  float v = d * invM - mu * mu;
#pragma unroll
  for (int o = 32; o > 0; o >>= 1) v += __shfl_xor(v, o);
  __shared__ float wsum[4];
  if ((i & 63) == 0) wsum[i >> 6] = v;
  __syncthreads();
  if (i == 0) {
    const float n = wsum[0] + wsum[1] + wsum[2] + wsum[3];
    invn[b]  = 1.0f / n;
    sqrtn[b] = sqrtf(n);
  }
}

// ---------------------------------------------------------------------------
// reduceprep: cov = (sum_s p_s)/M - mu mu^T (never stored);
// Y0 = cov*invn (bf16), Z1 = 1.5I - 0.5*Y0 (bf16)
// grid 2048 x 256, one float4-of-cov per thread
// ---------------------------------------------------------------------------
__global__ __launch_bounds__(256)
void reduceprep_kernel(const float* __restrict__ parts, const float* __restrict__ rs,
                       const float* __restrict__ invn,
                       ushort* __restrict__ Y0, ushort* __restrict__ Z1) {
  const int idx = blockIdx.x * 256 + threadIdx.x;   // 524288 float4
  const int b   = idx >> 14;
  const int rem = idx & 16383;
  const int i   = rem >> 6;
  const int j   = (rem & 63) * 4;
  const float invM = 1.0f / (float)M_;
  const float4* p4 = (const float4*)parts;

  float4 g = {0.f, 0.f, 0.f, 0.f};
  float  mi = 0.f;
  float4 mj = {0.f, 0.f, 0.f, 0.f};
#pragma unroll
  for (int s = 0; s < 8; ++s) {
    const float4 gs = p4[(size_t)s * (MATF / 4) + idx];
    g.x += gs.x; g.y += gs.y; g.z += gs.z; g.w += gs.w;
    const float* rrow = rs + b * 2048 + s * 256;
    mi += rrow[i];
    const float4 ms = *(const float4*)(rrow + j);
    mj.x += ms.x; mj.y += ms.y; mj.z += ms.z; mj.w += ms.w;
  }
  mi *= invM;
  const float in = invn[b];
  float y0 = (g.x * invM - mi * (mj.x * invM)) * in;
  float y1 = (g.y * invM - mi * (mj.y * invM)) * in;
  float y2 = (g.z * invM - mi * (mj.z * invM)) * in;
  float y3 = (g.w * invM - mi * (mj.w * invM)) * in;

  ushort4_t yv, zv;
  yv[0] = f2bf(y0); yv[1] = f2bf(y1); yv[2] = f2bf(y2); yv[3] = f2bf(y3);
  zv[0] = f2bf((j + 0 == i ? 1.5f : 0.f) - 0.5f * y0);
  zv[1] = f2bf((j + 1 == i ? 1.5f : 0.f) - 0.5f * y1);
  zv[2] = f2bf((j + 2 == i ? 1.5f : 0.f) - 0.5f * y2);
  zv[3] = f2bf((j + 3 == i ? 1.5f : 0.f) - 0.5f * y3);
  ((ushort4_t*)Y0)[idx] = yv;
  ((ushort4_t*)Z1)[idx] = zv;
}

// ---------------------------------------------------------------------------
// gemm_ns (bf16 in/out): batched 256x256x256, 64x64 tiles.
// B operand row-major (all matrices symmetric). global_load_lds staging with
// pre-swizzled source (linear LDS dest, swizzled ds_read). Modes:
//   MODE_T : O0 = 1.5 I - 0.5 * (A0 @ Bm)          grid 512
//   MODE_W : O0 = A0 @ Bm ; O1 = A1 @ Bm           grid 1024
//   MODE_I0: O0 = 1.5 * A0 - 0.5 * (A0 @ Bm)       grid 512
// ---------------------------------------------------------------------------
#define MODE_T 0
#define MODE_W 1
#define MODE_I0 2

template <int MODE>
__global__ __launch_bounds__(256)
void gemm_ns(const ushort* __restrict__ A0, const ushort* __restrict__ A1,
             const ushort* __restrict__ Bm,
             ushort* __restrict__ O0, ushort* __restrict__ O1) {
  const int bid0 = blockIdx.x;
  int bid = (MODE == MODE_W) ? ((bid0 & 7) * 128 + (bid0 >> 3))
                             : ((bid0 & 7) * 64 + (bid0 >> 3));
  const ushort* Aall = A0;
  ushort* Oall = O0;
  if (MODE == MODE_W && bid >= 512) { bid -= 512; Aall = A1; Oall = O1; }
  const int b    = bid >> 4;
  const int tile = bid & 15;
  const int rb   = (tile >> 2) * 64;
  const int cb   = (tile & 3) * 64;
  const ushort* Ap = Aall + ((size_t)b << 16) + rb * C_;
  const ushort* Bp = Bm   + ((size_t)b << 16) + cb * C_;
  ushort* Op = Oall + ((size_t)b << 16);

  __shared__ ushort As[64 * 64];
  __shared__ ushort Bs[64 * 64];

  const int t    = threadIdx.x;
  const int lane = t & 63;
  const int wid  = t >> 6;
  const int wr   = wid >> 1, wc = wid & 1;   // wave -> 32x32 subtile

  // staging source geometry (per global_load_lds issue q: rows q*32 + (t>>3))
  const int srow0 = t >> 3;                  // issue 0 row
  const int sc0   = (t & 7) ^ (srow0 & 7);   // pre-swizzled 16B chunk
  const int srow1 = 32 + srow0;
  const int sc1   = (t & 7) ^ (srow1 & 7);

  f32x4 acc[2][2];
#pragma unroll
  for (int m = 0; m < 2; ++m)
#pragma unroll
    for (int n = 0; n < 2; ++n) acc[m][n] = f32x4{0.f, 0.f, 0.f, 0.f};

  for (int k0 = 0; k0 < C_; k0 += 64) {
    __syncthreads();
    gl_lds16(Ap + (size_t)srow0 * C_ + k0 + sc0 * 8, (ushort*)((char*)As + wid * 1024));
    gl_lds16(Ap + (size_t)srow1 * C_ + k0 + sc1 * 8, (ushort*)((char*)As + 4096 + wid * 1024));
    gl_lds16(Bp + (size_t)srow0 * C_ + k0 + sc0 * 8, (ushort*)((char*)Bs + wid * 1024));
    gl_lds16(Bp + (size_t)srow1 * C_ + k0 + sc1 * 8, (ushort*)((char*)Bs + 4096 + wid * 1024));
    __syncthreads();
#pragma unroll
    for (int kk = 0; kk < 2; ++kk) {
      short8 af[2], bfr[2];
      const int slot = kk * 4 + (lane >> 4);
#pragma unroll
      for (int m = 0; m < 2; ++m) {
        const int ar = wr * 32 + m * 16 + (lane & 15);
        af[m] = *(const short8*)((const char*)As + ar * 128 + ((slot * 16) ^ ((ar & 7) << 4)));
      }
#pragma unroll
      for (int n = 0; n < 2; ++n) {
        const int br = wc * 32 + n * 16 + (lane & 15);
        bfr[n] = *(const short8*)((const char*)Bs + br * 128 + ((slot * 16) ^ ((br & 7) << 4)));
      }
#pragma unroll
      for (int m = 0; m < 2; ++m)
#pragma unroll
        for (int n = 0; n < 2; ++n)
          acc[m][n] = __builtin_amdgcn_mfma_f32_16x16x32_bf16(af[m], bfr[n], acc[m][n], 0, 0, 0);
    }
  }

#pragma unroll
  for (int m = 0; m < 2; ++m)
#pragma unroll
    for (int n = 0; n < 2; ++n)
#pragma unroll
      for (int r = 0; r < 4; ++r) {
        const int lr = wr * 32 + m * 16 + ((lane >> 4) * 4) + r;
        const int lc = wc * 32 + n * 16 + (lane & 15);
        const float v = acc[m][n][r];
        float o;
        if (MODE == MODE_T)       o = (((rb + lr) == (cb + lc)) ? 1.5f : 0.0f) - 0.5f * v;
        else if (MODE == MODE_W)  o = v;
        else /* MODE_I0 */        o = 1.5f * bf2f(Ap[lr * C_ + (cb + lc)]) - 0.5f * v;
        Op[(size_t)(rb + lr) * C_ + (cb + lc)] = f2bf(o);
      }
}

// ---------------------------------------------------------------------------
// final: u = colmean(Y4); v = sqrtn * (u^T T4); MLP -> a[b][c]
// ---------------------------------------------------------------------------
__global__ __launch_bounds__(256)
void final_kernel(const ushort* __restrict__ Y, const ushort* __restrict__ T,
                  const float* __restrict__ sqrtn,
                  const float* __restrict__ w1, const float* __restrict__ b1,
                  const float* __restrict__ w2, const float* __restrict__ b2,
                  float* __restrict__ a) {
  const int b = blockIdx.x;
  const int c = threadIdx.x;
  __shared__ float u[C_], vv[C_], h[32];
  const ushort* Yb = Y + ((size_t)b << 16);
  const ushort* Tb = T + ((size_t)b << 16);

  float s = 0.f;
  for (int i = 0; i < C_; ++i) s += bf2f(Yb[(size_t)i * C_ + c]);
  u[c] = s * (1.0f / (float)C_);
  __syncthreads();

  float acc = 0.f;
  for (int k = 0; k < C_; ++k) acc += u[k] * bf2f(Tb[(size_t)k * C_ + c]);
  vv[c] = acc * sqrtn[b];
  __syncthreads();

  if (c < 32) {
    float hh = b1[c];
    for (int k = 0; k < C_; ++k) hh += w1[c * C_ + k] * vv[k];
    h[c] = fmaxf(hh, 0.0f);
  }
  __syncthreads();

  float aa = b2[c];
#pragma unroll
  for (int o = 0; o < 32; ++o) aa += w2[c * 32 + o] * h[o];
  a[b * C_ + c] = 1.0f / (1.0f + expf(-aa));
}

// ---------------------------------------------------------------------------
// scale: out = a[b][c] * x
// ---------------------------------------------------------------------------
__global__ __launch_bounds__(256)
void scale_kernel(const float* __restrict__ x, const float* __restrict__ a,
                  float* __restrict__ out) {
  const int stride = gridDim.x * blockDim.x;
  const int n4 = B_ * C_ * M_ / 4;   // 8388608
  for (int i = blockIdx.x * blockDim.x + threadIdx.x; i < n4; i += stride) {
    const float4 v = ((const float4*)x)[i];
    const float s = a[i >> 10];
    float4 o = { v.x * s, v.y * s, v.z * s, v.w * s };
    ((float4*)out)[i] = o;
  }
}

// ---------------------------------------------------------------------------
extern "C" void kernel_launch(void* const* d_in, const int* in_sizes, int n_in,
                              void* d_out, int out_size, void* d_ws, size_t ws_size,
                              hipStream_t stream) {
  const float* x  = (const float*)d_in[0];
  const float* w1 = (const float*)d_in[1];
  const float* b1 = (const float*)d_in[2];
  const float* w2 = (const float*)d_in[3];
  const float* b2 = (const float*)d_in[4];
  float* out = (float*)d_out;

  float* ws = (float*)d_ws;
  float* parts = ws;                         // 8 * MATF floats (64 MB)
  float* rs    = ws + 8 * (size_t)MATF;      // 32*2048
  float* invn  = rs + 65536;
  float* sqrtn = invn + 32;
  float* a     = sqrtn + 32;                 // 32*256
  ushort* bfb  = (ushort*)(a + 8192);
  ushort* Yb0  = bfb;                        // each 2,097,152 ushorts (4 MB)
  ushort* Yb1  = bfb + 1 * (size_t)MATF;
  ushort* Zb0  = bfb + 2 * (size_t)MATF;
  ushort* Zb1  = bfb + 3 * (size_t)MATF;
  ushort* Tb   = bfb + 4 * (size_t)MATF;

  covpool_kernel<<<256, 1024, 0, stream>>>(x, parts, rs);
  trace_kernel<<<32, 256, 0, stream>>>(parts, rs, invn, sqrtn);
  reduceprep_kernel<<<2048, 256, 0, stream>>>(parts, rs, invn, Yb0, Zb0);

  // i=0 (Z=I): Y1 = 1.5 Y0 - 0.5 Y0@Y0 ; Z1 from reduceprep
  gemm_ns<MODE_I0><<<512, 256, 0, stream>>>(Yb0, nullptr, Yb0, Yb1, nullptr);
  // i=1
  gemm_ns<MODE_T><<<512, 256, 0, stream>>>(Zb0, nullptr, Yb1, Tb, nullptr);
  gemm_ns<MODE_W><<<1024, 256, 0, stream>>>(Yb1, Zb0, Tb, Yb0, Zb1);
  // i=2
  gemm_ns<MODE_T><<<512, 256, 0, stream>>>(Zb1, nullptr, Yb0, Tb, nullptr);
  gemm_ns<MODE_W><<<1024, 256, 0, stream>>>(Yb0, Zb1, Tb, Yb1, Zb0);
  // i=3
  gemm_ns<MODE_T><<<512, 256, 0, stream>>>(Zb0, nullptr, Yb1, Tb, nullptr);
  gemm_ns<MODE_W><<<1024, 256, 0, stream>>>(Yb1, Zb0, Tb, Yb0, Zb1);
  // i=4: only T4, then matvec in final
  gemm_ns<MODE_T><<<512, 256, 0, stream>>>(Zb1, nullptr, Yb0, Tb, nullptr);

  final_kernel<<<32, 256, 0, stream>>>(Yb0, Tb, sqrtn, w1, b1, w2, b2, a);
  scale_kernel<<<4096, 256, 0, stream>>>(x, a, out);
}